// Round 2
// 638.202 us; speedup vs baseline: 1.1853x; 1.1853x over previous
//
#include <hip/hip_runtime.h>
#include <math.h>

#define BB 512
#define NN 200
#define DD 128
#define BNROWS (BB*NN)   // 102400

typedef float f32x4 __attribute__((ext_vector_type(4)));
typedef short bf16x8 __attribute__((ext_vector_type(8)));

#define MFMA16(a,b,c) __builtin_amdgcn_mfma_f32_16x16x32_bf16(a,b,c,0,0,0)

// ---------------- workspace layout (bytes) ----------------
// Refactor: gi = (A_in H)(W1 w_in)^T + (A_out H)(W2 w_out)^T
//              + rs_in (W1 b_in)^T + rs_out (W2 b_out)^T
//              + 1 (W1 b_iah + W2 b_oah + b_ih)^T
// => k1's dense GEMMs eliminated; M1/M2 are 384x128 precomputed.
#define OFF_ZHI   ((size_t)0)
#define OFF_ZLO   (OFF_ZHI + (size_t)BNROWS*384*2)
#define OFF_HT    (OFF_ZLO + (size_t)BNROWS*256*2)
#define OFF_M1    (OFF_HT  + (size_t)BB*128*224*2)
#define OFF_M2    (OFF_M1  + (size_t)384*128*4)
#define OFF_WH    (OFF_M2  + (size_t)384*128*4)
#define OFF_WL    (OFF_WH  + (size_t)512*384*2)
#define OFF_CC    (OFF_WL  + (size_t)512*384*2)
#define OFF_U1V   (OFF_CC  + 512*4)
#define OFF_U2V   (OFF_U1V + 512*4)
#define OFF_U1    (OFF_U2V + 512*4)
#define OFF_U2    (OFF_U1  + 384*4)
#define OFF_C0    (OFF_U2  + 384*4)
#define OFF_RSI   (OFF_C0  + 384*4)
#define OFF_RSO   (OFF_RSI + (size_t)BNROWS*4)
#define WS_BYTES  (OFF_RSO + (size_t)BNROWS*4)

__device__ inline unsigned short f2bf(float x) {
  unsigned int u = __float_as_uint(x);
  unsigned int r = u + 0x7FFFu + ((u >> 16) & 1u);   // RNE
  return (unsigned short)(r >> 16);
}
__device__ inline float bf2f(unsigned short h) {
  return __uint_as_float(((unsigned int)h) << 16);
}

// ---------------- kprep: M1 = W1 @ w_in, M2 = W2 @ w_out; u1,u2,c0 vectors ----
// W1 = w_ih[:, :128], W2 = w_ih[:, 128:256].  One block per output row j.
__global__ __launch_bounds__(128) void kprep(
    const float* __restrict__ w_ih, const float* __restrict__ w_in,
    const float* __restrict__ w_out, const float* __restrict__ b_in,
    const float* __restrict__ b_out, const float* __restrict__ b_iah,
    const float* __restrict__ b_oah, const float* __restrict__ b_ih,
    float* __restrict__ M1, float* __restrict__ M2,
    float* __restrict__ u1, float* __restrict__ u2, float* __restrict__ c0) {
  __shared__ float wrow[256];
  const int j = blockIdx.x;        // 0..383
  const int k = threadIdx.x;       // 0..127
  wrow[k]       = w_ih[(size_t)j * 256 + k];
  wrow[128 + k] = w_ih[(size_t)j * 256 + 128 + k];
  __syncthreads();
  float a1 = 0.f, a2 = 0.f;
  for (int t = 0; t < 128; ++t) {
    a1 = fmaf(wrow[t],       w_in[t * 128 + k],  a1);
    a2 = fmaf(wrow[128 + t], w_out[t * 128 + k], a2);
  }
  M1[j * 128 + k] = a1;
  M2[j * 128 + k] = a2;
  if (k == 0) {
    float s1 = 0.f, s2 = 0.f, s0 = 0.f;
    for (int t = 0; t < 128; ++t) {
      s1 = fmaf(wrow[t], b_in[t], s1);
      s2 = fmaf(wrow[128 + t], b_out[t], s2);
      s0 = fmaf(wrow[t], b_iah[t], s0);
      s0 = fmaf(wrow[128 + t], b_oah[t], s0);
    }
    u1[j] = s1; u2[j] = s2; c0[j] = s0 + b_ih[j];
  }
}

// ---------------- Wcat build: permuted 512-col [r | i | n_P | n_h], K=384 ------
// K layout now [P_in(0:128) | P_out(128:256) | H(256:384)].
__global__ void wcat_build(const float* __restrict__ M1, const float* __restrict__ M2,
                           const float* __restrict__ w_hh, const float* __restrict__ b_hh,
                           const float* __restrict__ u1, const float* __restrict__ u2,
                           const float* __restrict__ c0,
                           unsigned short* __restrict__ Wh, unsigned short* __restrict__ Wl,
                           float* __restrict__ cc, float* __restrict__ u1v,
                           float* __restrict__ u2v) {
  int idx = blockIdx.x * 256 + threadIdx.x;   // 512*384
  if (idx >= 512 * 384) return;
  int jp = idx / 384, k = idx - jp * 384;
  int nh = jp >> 8, ng = (jp >> 7) & 1, t = (jp >> 4) & 7, q = jp & 15;
  int blk = t >> 1, s = t & 1;
  int c = nh * 64 + ng * 32 + s * 16 + q;
  int g = (blk <= 1) ? blk : 2;
  int j = g * 128 + c;
  float val;
  if (k < 128)      val = (blk == 3) ? 0.f : M1[j * 128 + k];
  else if (k < 256) val = (blk == 3) ? 0.f : M2[j * 128 + (k - 128)];
  else              val = (blk == 2) ? 0.f : w_hh[(size_t)j * 128 + (k - 256)];
  unsigned short h = f2bf(val);
  Wh[idx] = h;
  Wl[idx] = f2bf(val - bf2f(h));
  if (k == 0) {
    float ccv, a1, a2;
    if (blk == 0)      { ccv = c0[c] + b_hh[c];             a1 = u1[c];       a2 = u2[c]; }
    else if (blk == 1) { ccv = c0[128 + c] + b_hh[128 + c]; a1 = u1[128 + c]; a2 = u2[128 + c]; }
    else if (blk == 2) { ccv = c0[256 + c];                 a1 = u1[256 + c]; a2 = u2[256 + c]; }
    else               { ccv = b_hh[256 + c];               a1 = 0.f;         a2 = 0.f; }
    cc[jp] = ccv; u1v[jp] = a1; u2v[jp] = a2;
  }
}

// ---------------- K1: emb gather -> Z_hi hidden cols + transposed bf16 HT -----
__global__ __launch_bounds__(256) void k1_gather(
    const int* __restrict__ x, const float* __restrict__ emb,
    unsigned short* __restrict__ hT, unsigned short* __restrict__ Z_hi) {
  __shared__ float hid[32][132];
  const int t = threadIdx.x;
  const int b = blockIdx.x;
  const int m0 = blockIdx.y * 32;
  for (int i = t; i < 32 * 128; i += 256) {
    int r = i >> 7, c = i & 127;
    int m = m0 + r;
    int rowc = b * 200 + (m < 200 ? m : 199);
    float h = emb[(size_t)x[rowc] * 128 + c];
    hid[r][c] = h;
    if (m < 200) Z_hi[(size_t)(b * 200 + m) * 384 + 256 + c] = f2bf(h);
  }
  __syncthreads();
  {
    int c = t >> 1, half = t & 1;
    bf16x8 p0, p1;
    #pragma unroll
    for (int j = 0; j < 16; ++j) {
      int ml = half * 16 + j;
      bool valid = (m0 + ml) < 200;
      float fv = valid ? hid[ml][c] : 0.f;
      if (j < 8) p0[j] = (short)f2bf(fv);
      else       p1[j - 8] = (short)f2bf(fv);
    }
    size_t base = ((size_t)(b * 128 + c)) * 224 + m0 + half * 16;
    *(bf16x8*)&hT[base]     = p0;
    *(bf16x8*)&hT[base + 8] = p1;
  }
}

// ---------------- K2: P = A @ H via MFMA (A split hi/lo), plus rowsums --------
__global__ __launch_bounds__(256) void k2_amm(
    const float* __restrict__ A, const unsigned short* __restrict__ hT,
    unsigned short* __restrict__ Z_hi, unsigned short* __restrict__ Z_lo,
    float* __restrict__ rs_in, float* __restrict__ rs_out) {
  __shared__ alignas(16) unsigned short Ainh[64][32];
  __shared__ alignas(16) unsigned short Ainl[64][32];
  __shared__ alignas(16) unsigned short Aouth[64][32];
  __shared__ alignas(16) unsigned short Aoutl[64][32];
  __shared__ alignas(16) unsigned short Bv[128][32];
  const int t = threadIdx.x;
  const int b = blockIdx.x;
  const int m0 = blockIdx.y * 64;
  const int wv_id = t >> 6, lane = t & 63;
  const int q = lane & 15, quad = lane >> 4;
  const int sel = wv_id >> 1, nh2 = wv_id & 1;
  f32x4 acc[4][4];
  #pragma unroll
  for (int i = 0; i < 4; ++i)
    #pragma unroll
    for (int j = 0; j < 4; ++j) acc[i][j] = 0.f;
  float rsi = 0.f, rso = 0.f;

  for (int k0 = 0; k0 < 224; k0 += 32) {
    __syncthreads();
    {  // stage A (fp32 -> bf16 hi+lo), accumulate row sums for bias folding
      int m = t >> 2, seg = t & 3;
      int gm = m0 + m, kb = k0 + seg * 8;
      float fin[8], fot[8];
      bool v = (gm < 200) && (kb < 200);
      if (v) {
        const float* arow = A + (size_t)(b * 200 + gm) * 400;
        f32x4 p0 = *(const f32x4*)(arow + kb);
        f32x4 p1 = *(const f32x4*)(arow + kb + 4);
        f32x4 q0 = *(const f32x4*)(arow + 200 + kb);
        f32x4 q1 = *(const f32x4*)(arow + 200 + kb + 4);
        fin[0]=p0.x; fin[1]=p0.y; fin[2]=p0.z; fin[3]=p0.w;
        fin[4]=p1.x; fin[5]=p1.y; fin[6]=p1.z; fin[7]=p1.w;
        fot[0]=q0.x; fot[1]=q0.y; fot[2]=q0.z; fot[3]=q0.w;
        fot[4]=q1.x; fot[5]=q1.y; fot[6]=q1.z; fot[7]=q1.w;
      } else {
        #pragma unroll
        for (int e = 0; e < 8; ++e) { fin[e] = 0.f; fot[e] = 0.f; }
      }
      bf16x8 ih, il, oh, ol;
      #pragma unroll
      for (int e = 0; e < 8; ++e) {
        rsi += fin[e]; rso += fot[e];
        unsigned short h1 = f2bf(fin[e]);
        ih[e] = (short)h1; il[e] = (short)f2bf(fin[e] - bf2f(h1));
        unsigned short h2 = f2bf(fot[e]);
        oh[e] = (short)h2; ol[e] = (short)f2bf(fot[e] - bf2f(h2));
      }
      *(bf16x8*)&Ainh[m][seg * 8]  = ih;
      *(bf16x8*)&Ainl[m][seg * 8]  = il;
      *(bf16x8*)&Aouth[m][seg * 8] = oh;
      *(bf16x8*)&Aoutl[m][seg * 8] = ol;
    }
    #pragma unroll
    for (int p = 0; p < 2; ++p) {  // stage B = H^T (bf16, zero-padded to 224)
      int i = p * 256 + t;
      int c = i >> 2, seg = i & 3;
      size_t off = ((size_t)(b * 128 + c)) * 224 + k0 + seg * 8;
      *(bf16x8*)&Bv[c][seg * 8] = *(const bf16x8*)(hT + off);
    }
    __syncthreads();
    const unsigned short (*Ath)[32] = sel ? Aouth : Ainh;
    const unsigned short (*Atl)[32] = sel ? Aoutl : Ainl;
    bf16x8 ah[4], al[4];
    #pragma unroll
    for (int mt = 0; mt < 4; ++mt) {
      ah[mt] = *(const bf16x8*)&Ath[mt * 16 + q][quad * 8];
      al[mt] = *(const bf16x8*)&Atl[mt * 16 + q][quad * 8];
    }
    #pragma unroll
    for (int nt = 0; nt < 4; ++nt) {
      bf16x8 bb = *(const bf16x8*)&Bv[nh2 * 64 + nt * 16 + q][quad * 8];
      #pragma unroll
      for (int mt = 0; mt < 4; ++mt) {
        acc[mt][nt] = MFMA16(ah[mt], bb, acc[mt][nt]);
        acc[mt][nt] = MFMA16(al[mt], bb, acc[mt][nt]);
      }
    }
  }
  const int colbase = sel * 128;
  #pragma unroll
  for (int nt = 0; nt < 4; ++nt) {
    int c = nh2 * 64 + nt * 16 + q;
    #pragma unroll
    for (int mt = 0; mt < 4; ++mt) {
      #pragma unroll
      for (int r = 0; r < 4; ++r) {
        int m = m0 + mt * 16 + quad * 4 + r;
        if (m < 200) {
          float v = acc[mt][nt][r];
          unsigned short hs = f2bf(v);
          size_t row = (size_t)(b * 200 + m);
          Z_hi[row * 384 + colbase + c] = hs;
          Z_lo[row * 256 + colbase + c] = f2bf(v - bf2f(hs));
        }
      }
    }
  }
  // reduce row sums across the 4 seg-lanes of each row, store once
  rsi += __shfl_xor(rsi, 1); rsi += __shfl_xor(rsi, 2);
  rso += __shfl_xor(rso, 1); rso += __shfl_xor(rso, 2);
  {
    int m = t >> 2, gm = m0 + m;
    if ((t & 3) == 0 && gm < 200) {
      rs_in[(size_t)b * 200 + gm]  = rsi;
      rs_out[(size_t)b * 200 + gm] = rso;
    }
  }
}

// ---------------- K3: fused gi/gh GEMM (split-bf16 MFMA) + gates ----------------
__global__ __launch_bounds__(256) void k3_gates(
    const unsigned short* __restrict__ Z_hi, const unsigned short* __restrict__ Z_lo,
    const unsigned short* __restrict__ Wh, const unsigned short* __restrict__ Wl,
    const float* __restrict__ cc, const float* __restrict__ u1v,
    const float* __restrict__ u2v, const float* __restrict__ rs_in,
    const float* __restrict__ rs_out, float* __restrict__ out) {
  __shared__ alignas(16) unsigned short Ah[128][32];
  __shared__ alignas(16) unsigned short Al[128][32];
  __shared__ alignas(16) unsigned short WhS[256][32];
  __shared__ alignas(16) unsigned short WlS[256][32];
  const int t = threadIdx.x;
  const int w = t >> 6, lane = t & 63;
  const int q = lane & 15, quad = lane >> 4;
  const int mh = w >> 1, ng = w & 1;
  const size_t rbase = (size_t)blockIdx.x * 128;
  const int nh = blockIdx.y;

  f32x4 acc[4][8];
  #pragma unroll
  for (int i = 0; i < 4; ++i)
    #pragma unroll
    for (int j = 0; j < 8; ++j) acc[i][j] = 0.f;

  // ---- phase 1: k in [0,256) — P part; tiles 0..5 (r,i,n_P); 3-term ----
  for (int kc = 0; kc < 8; ++kc) {
    const int k0 = kc * 32;
    __syncthreads();
    #pragma unroll
    for (int p = 0; p < 2; ++p) {
      int i = p * 256 + t;
      int m = i >> 2, seg = i & 3;
      *(bf16x8*)&Ah[m][seg * 8] =
          *(const bf16x8*)(Z_hi + (rbase + m) * 384 + k0 + seg * 8);
      *(bf16x8*)&Al[m][seg * 8] =
          *(const bf16x8*)(Z_lo + (rbase + m) * 256 + k0 + seg * 8);
    }
    #pragma unroll
    for (int p = 0; p < 4; ++p) {
      int i = p * 256 + t;
      int j = i >> 2, seg = i & 3;
      size_t off = (size_t)(nh * 256 + j) * 384 + k0 + seg * 8;
      *(bf16x8*)&WhS[j][seg * 8] = *(const bf16x8*)(Wh + off);
      *(bf16x8*)&WlS[j][seg * 8] = *(const bf16x8*)(Wl + off);
    }
    __syncthreads();
    bf16x8 ah[4], al[4];
    #pragma unroll
    for (int mt = 0; mt < 4; ++mt) {
      ah[mt] = *(const bf16x8*)&Ah[mh * 64 + mt * 16 + q][quad * 8];
      al[mt] = *(const bf16x8*)&Al[mh * 64 + mt * 16 + q][quad * 8];
    }
    #pragma unroll
    for (int tt = 0; tt < 6; ++tt) {
      bf16x8 bh = *(const bf16x8*)&WhS[ng * 128 + tt * 16 + q][quad * 8];
      bf16x8 bl = *(const bf16x8*)&WlS[ng * 128 + tt * 16 + q][quad * 8];
      #pragma unroll
      for (int mt = 0; mt < 4; ++mt) {
        acc[mt][tt] = MFMA16(ah[mt], bh, acc[mt][tt]);
        acc[mt][tt] = MFMA16(ah[mt], bl, acc[mt][tt]);
        acc[mt][tt] = MFMA16(al[mt], bh, acc[mt][tt]);
      }
    }
  }
  // ---- phase 2: k in [256,384) — hidden part; tiles {0,1,2,3,6,7}; 2-term ----
  for (int kc = 8; kc < 12; ++kc) {
    const int k0 = kc * 32;
    __syncthreads();
    #pragma unroll
    for (int p = 0; p < 2; ++p) {
      int i = p * 256 + t;
      int m = i >> 2, seg = i & 3;
      *(bf16x8*)&Ah[m][seg * 8] =
          *(const bf16x8*)(Z_hi + (rbase + m) * 384 + k0 + seg * 8);
    }
    #pragma unroll
    for (int p = 0; p < 4; ++p) {
      int i = p * 256 + t;
      int j = i >> 2, seg = i & 3;
      size_t off = (size_t)(nh * 256 + j) * 384 + k0 + seg * 8;
      *(bf16x8*)&WhS[j][seg * 8] = *(const bf16x8*)(Wh + off);
      *(bf16x8*)&WlS[j][seg * 8] = *(const bf16x8*)(Wl + off);
    }
    __syncthreads();
    bf16x8 ah[4];
    #pragma unroll
    for (int mt = 0; mt < 4; ++mt)
      ah[mt] = *(const bf16x8*)&Ah[mh * 64 + mt * 16 + q][quad * 8];
    #pragma unroll
    for (int ti = 0; ti < 6; ++ti) {
      const int tt = (ti < 4) ? ti : ti + 2;   // tiles 0,1,2,3,6,7
      bf16x8 bh = *(const bf16x8*)&WhS[ng * 128 + tt * 16 + q][quad * 8];
      bf16x8 bl = *(const bf16x8*)&WlS[ng * 128 + tt * 16 + q][quad * 8];
      #pragma unroll
      for (int mt = 0; mt < 4; ++mt) {
        acc[mt][tt] = MFMA16(ah[mt], bh, acc[mt][tt]);
        acc[mt][tt] = MFMA16(ah[mt], bl, acc[mt][tt]);
      }
    }
  }
  // gates epilogue with folded rank-1 biases
  const int jb = nh * 256 + ng * 128;
  float cs[2][4], a1s[2][3], a2s[2][3];
  #pragma unroll
  for (int s = 0; s < 2; ++s) {
    #pragma unroll
    for (int gb = 0; gb < 4; ++gb) cs[s][gb] = cc[jb + (gb * 2 + s) * 16 + q];
    #pragma unroll
    for (int gb = 0; gb < 3; ++gb) {
      a1s[s][gb] = u1v[jb + (gb * 2 + s) * 16 + q];
      a2s[s][gb] = u2v[jb + (gb * 2 + s) * 16 + q];
    }
  }
  #pragma unroll
  for (int mt = 0; mt < 4; ++mt) {
    #pragma unroll
    for (int r = 0; r < 4; ++r) {
      size_t row = rbase + mh * 64 + mt * 16 + quad * 4 + r;
      float rin = rs_in[row], rot = rs_out[row];
      #pragma unroll
      for (int s = 0; s < 2; ++s) {
        int c = nh * 64 + ng * 32 + s * 16 + q;
        float sr  = acc[mt][0 + s][r] + cs[s][0] + rin * a1s[s][0] + rot * a2s[s][0];
        float si  = acc[mt][2 + s][r] + cs[s][1] + rin * a1s[s][1] + rot * a2s[s][1];
        float ani = acc[mt][4 + s][r] + cs[s][2] + rin * a1s[s][2] + rot * a2s[s][2];
        float anh = acc[mt][6 + s][r] + cs[s][3];
        float g_rs = 1.f / (1.f + expf(-sr));
        float g_in = 1.f / (1.f + expf(-si));
        float g_ot = tanhf(ani + g_rs * anh);
        float h = bf2f(Z_hi[row * 384 + 256 + c]);
        out[row * 128 + c] = g_ot + g_in * (h - g_ot);
      }
    }
  }
}

extern "C" void kernel_launch(void* const* d_in, const int* in_sizes, int n_in,
                              void* d_out, int out_size, void* d_ws, size_t ws_size,
                              hipStream_t stream) {
  const int*   x     = (const int*)d_in[0];
  const float* A     = (const float*)d_in[1];
  const float* emb   = (const float*)d_in[2];
  const float* w_in  = (const float*)d_in[3];
  const float* b_in  = (const float*)d_in[4];
  const float* w_out = (const float*)d_in[5];
  const float* b_out = (const float*)d_in[6];
  const float* w_ih  = (const float*)d_in[7];
  const float* b_ih  = (const float*)d_in[8];
  const float* w_hh  = (const float*)d_in[9];
  const float* b_hh  = (const float*)d_in[10];
  const float* b_iah = (const float*)d_in[11];
  const float* b_oah = (const float*)d_in[12];
  float* out = (float*)d_out;
  char* ws = (char*)d_ws;

  if (ws_size < WS_BYTES) return;

  unsigned short* Z_hi = (unsigned short*)(ws + OFF_ZHI);
  unsigned short* Z_lo = (unsigned short*)(ws + OFF_ZLO);
  unsigned short* hT   = (unsigned short*)(ws + OFF_HT);
  float* M1 = (float*)(ws + OFF_M1);
  float* M2 = (float*)(ws + OFF_M2);
  unsigned short* Wh = (unsigned short*)(ws + OFF_WH);
  unsigned short* Wl = (unsigned short*)(ws + OFF_WL);
  float* ccv = (float*)(ws + OFF_CC);
  float* u1v = (float*)(ws + OFF_U1V);
  float* u2v = (float*)(ws + OFF_U2V);
  float* u1  = (float*)(ws + OFF_U1);
  float* u2  = (float*)(ws + OFF_U2);
  float* c0  = (float*)(ws + OFF_C0);
  float* rs_in  = (float*)(ws + OFF_RSI);
  float* rs_out = (float*)(ws + OFF_RSO);

  kprep<<<384, 128, 0, stream>>>(w_ih, w_in, w_out, b_in, b_out, b_iah, b_oah,
                                 b_ih, M1, M2, u1, u2, c0);
  wcat_build<<<(512 * 384 + 255) / 256, 256, 0, stream>>>(M1, M2, w_hh, b_hh,
                                                          u1, u2, c0, Wh, Wl,
                                                          ccv, u1v, u2v);
  dim3 g1(BB, 7);
  k1_gather<<<g1, 256, 0, stream>>>(x, emb, hT, Z_hi);
  dim3 g2(BB, 4);
  k2_amm<<<g2, 256, 0, stream>>>(A, hT, Z_hi, Z_lo, rs_in, rs_out);
  dim3 g3(BNROWS / 128, 2);
  k3_gates<<<g3, 256, 0, stream>>>(Z_hi, Z_lo, Wh, Wl, ccv, u1v, u2v,
                                   rs_in, rs_out, out);
}